// Round 2
// baseline (5415.736 us; speedup 1.0000x reference)
//
#include <hip/hip_runtime.h>

// ---------------------------------------------------------------------------
// Decoder: B=32, T=64, S=64, V=32000, E=H=512, L=2
// Structure:
//   prep:  cvt W_out->bf16 ; encP = enc @ W_a in FP32 (recurrence-critical!)
//   loop t=0..63 (3 kernels/step, fp32 recurrent state, ping-pong buffers):
//     phase1: scores = encP . h1 ; softmax ; context      (32 blocks, 1/b)
//     phase2: LSTM cell 0 (gates from [x_t | ctx | h0])   (512 blocks)
//     phase3: LSTM cell 1 (gates from [h0 | h1])          (512 blocks)
//     phase1/3 also write cat[b*T+t] = [h1 | ctx] as bf16 (forward-only)
//   epilogue: out = cat @ W_out^T + b_out  (128x128 bf16 MFMA GEMM, M=2048,
//             N=32000, K=1024) ; copy h_f/c_f.
// Precision rule: anything that FEEDS BACK into the recurrence stays fp32
// (bf16 logit noise is amplified by the peaked softmax over 64 steps).
// bf16 only on the forward-only output projection (error ~0.005 << 0.12).
// ---------------------------------------------------------------------------

typedef __attribute__((ext_vector_type(8))) __bf16 bf16x8;
typedef __attribute__((ext_vector_type(4))) float f32x4;

__device__ __forceinline__ short f2b(float f) {
  unsigned u = __builtin_bit_cast(unsigned, f);
  u += 0x7fffu + ((u >> 16) & 1u);          // round-to-nearest-even
  return (short)(u >> 16);
}

__device__ __forceinline__ float wave_sum(float v) {
  for (int off = 32; off > 0; off >>= 1) v += __shfl_down(v, off);
  return v;                                  // lane 0 holds the sum
}

__device__ __forceinline__ float sigm(float x) { return 1.f / (1.f + expf(-x)); }

// ---------------- converts ----------------
__global__ __launch_bounds__(256) void cvt_bf16_k(const float* __restrict__ in,
                                                  short* __restrict__ out, long n) {
  long stride = (long)gridDim.x * 256 * 4;
  for (long i = ((long)blockIdx.x * 256 + threadIdx.x) * 4; i < n; i += stride) {
    float4 v = *(const float4*)&in[i];
    short4 o; o.x = f2b(v.x); o.y = f2b(v.y); o.z = f2b(v.z); o.w = f2b(v.w);
    *(short4*)&out[i] = o;
  }
}

__global__ __launch_bounds__(256) void init_states_k(const float* __restrict__ hidden,
                                                     const float* __restrict__ cell,
                                                     float* h0, float* h1, float* c0, float* c1) {
  int i = blockIdx.x * 256 + threadIdx.x;   // grid 64 -> 16384
  h0[i] = hidden[i]; h1[i] = hidden[16384 + i];
  c0[i] = cell[i];   c1[i] = cell[16384 + i];
}

__global__ __launch_bounds__(256) void fin_states_k(const float* __restrict__ h0,
                                                    const float* __restrict__ h1,
                                                    const float* __restrict__ c0,
                                                    const float* __restrict__ c1,
                                                    float* __restrict__ out) {
  int i = blockIdx.x * 256 + threadIdx.x;   // grid 64
  out[i] = h0[i]; out[16384 + i] = h1[i];
  out[32768 + i] = c0[i]; out[49152 + i] = c1[i];
}

// ---------------- fp32 GEMM: C[MxN] = A[MxK] @ B[KxN], 64x64 tile, BK=16 ----
// Used ONLY for encP = enc @ W_a (1.07 GFLOP, one-time). FP32 because scores
// feed the softmax->recurrence loop and bf16 noise there diverges.
__global__ __launch_bounds__(256) void gemm_f32_k(
    const float* __restrict__ A, const float* __restrict__ B,
    float* __restrict__ C, int M, int N, int K, int ldb) {
  __shared__ float As[16][65];
  __shared__ float Bs[16][64];
  int tid = threadIdx.x;
  int tm = blockIdx.y * 64, tn = blockIdx.x * 64;
  int ty = tid >> 4, tx = tid & 15;
  float acc[4][4] = {};
  for (int k0 = 0; k0 < K; k0 += 16) {
    __syncthreads();
    for (int l = 0; l < 4; l++) {
      int idx = l * 256 + tid;            // 0..1023
      int m = idx >> 4, kk = idx & 15;    // A tile: 64m x 16k
      As[kk][m] = A[(long)(tm + m) * K + k0 + kk];
      int kb = idx >> 6, n = idx & 63;    // B tile: 16k x 64n (coalesced)
      Bs[kb][n] = B[(long)(k0 + kb) * ldb + tn + n];
    }
    __syncthreads();
    for (int kk = 0; kk < 16; kk++) {
      float a[4], b[4];
      for (int i = 0; i < 4; i++) a[i] = As[kk][ty * 4 + i];
      for (int j = 0; j < 4; j++) b[j] = Bs[kk][tx * 4 + j];
      for (int i = 0; i < 4; i++)
        for (int j = 0; j < 4; j++) acc[i][j] += a[i] * b[j];
    }
  }
  for (int i = 0; i < 4; i++)
    for (int j = 0; j < 4; j++)
      C[(long)(tm + ty * 4 + i) * N + tn + tx * 4 + j] = acc[i][j];
}

// ---------------- bf16 MFMA GEMM: C[MxN] = A[MxK] * Bt[NxK]^T (+bias) -------
// 128x128 tile, BK=64, 256 thr (2x2 waves of 64x64), 16x16x32 MFMA,
// global_load_lds width-16 staging, XOR-swizzled LDS (2-way max conflict).
__global__ __launch_bounds__(256) void gemm_bf16(
    const short* __restrict__ A, const short* __restrict__ Bt,
    float* __restrict__ C, const float* __restrict__ bias1,
    int M, int N, int K, int lda, int ldb, int ldc) {
  __shared__ __align__(16) short lsA[8192];
  __shared__ __align__(16) short lsB[8192];
  int tid = threadIdx.x, lane = tid & 63, w = tid >> 6;
  int wm = w >> 1, wn = w & 1;
  int tm = blockIdx.y * 128, tn = blockIdx.x * 128;
  f32x4 acc[4][4] = {};
  int kts = K >> 6;
  for (int kt = 0; kt < kts; kt++) {
    int k0 = kt << 6;
    __syncthreads();
    for (int inst = 0; inst < 4; inst++) {
      int s = w * 256 + inst * 64 + lane;
      int row = s >> 3, cc = s & 7, c = cc ^ (row & 7);
      const short* ga = A + (long)(tm + row) * lda + k0 + c * 8;
      const short* gb = Bt + (long)(tn + row) * ldb + k0 + c * 8;
      __builtin_amdgcn_global_load_lds((const __attribute__((address_space(1))) void*)ga,
                                       (__attribute__((address_space(3))) void*)&lsA[s * 8],
                                       16, 0, 0);
      __builtin_amdgcn_global_load_lds((const __attribute__((address_space(1))) void*)gb,
                                       (__attribute__((address_space(3))) void*)&lsB[s * 8],
                                       16, 0, 0);
    }
    asm volatile("s_waitcnt vmcnt(0)" ::: "memory");
    __syncthreads();
    for (int ks = 0; ks < 2; ks++) {
      bf16x8 af[4], bfr[4];
      for (int mt = 0; mt < 4; mt++) {
        int row = wm * 64 + mt * 16 + (lane & 15);
        int c = ks * 4 + (lane >> 4);
        int slot = row * 8 + (c ^ (row & 7));
        af[mt] = *(const bf16x8*)&lsA[slot * 8];
      }
      for (int nt = 0; nt < 4; nt++) {
        int row = wn * 64 + nt * 16 + (lane & 15);
        int c = ks * 4 + (lane >> 4);
        int slot = row * 8 + (c ^ (row & 7));
        bfr[nt] = *(const bf16x8*)&lsB[slot * 8];
      }
      for (int mt = 0; mt < 4; mt++)
        for (int nt = 0; nt < 4; nt++)
          acc[mt][nt] = __builtin_amdgcn_mfma_f32_16x16x32_bf16(af[mt], bfr[nt], acc[mt][nt], 0, 0, 0);
    }
  }
  for (int nt = 0; nt < 4; nt++) {
    int ccol = tn + wn * 64 + nt * 16 + (lane & 15);
    float bsum = bias1 ? bias1[ccol] : 0.f;
    for (int mt = 0; mt < 4; mt++) {
      int r0 = tm + wm * 64 + mt * 16 + ((lane >> 4) << 2);
      f32x4 v = acc[mt][nt];
      for (int r = 0; r < 4; r++)
        C[(long)(r0 + r) * ldc + ccol] = v[r] + bsum;
    }
  }
}

// ---------------- phase 1: attention (one block per b) ----------------------
__global__ __launch_bounds__(256) void phase1_k(
    const float* __restrict__ encP, const float* __restrict__ enc,
    const float* __restrict__ h1_old, float* __restrict__ ctx,
    short* __restrict__ cat, int t) {
  int b = blockIdx.x;
  __shared__ __align__(16) float sh1[512];
  __shared__ float sattn[64];
  int tid = threadIdx.x, lane = tid & 63, w = tid >> 6;
  sh1[tid] = h1_old[b * 512 + tid];
  sh1[256 + tid] = h1_old[b * 512 + 256 + tid];
  __syncthreads();
  for (int i = 0; i < 16; i++) {
    int s = w * 16 + i;
    const float* ep = encP + (long)(b * 64 + s) * 512;
    float acc = 0.f;
    for (int kk = 0; kk < 2; kk++) {
      float4 ev = *(const float4*)&ep[(kk * 64 + lane) * 4];
      float4 hv = *(const float4*)&sh1[(kk * 64 + lane) * 4];
      acc += ev.x * hv.x + ev.y * hv.y + ev.z * hv.z + ev.w * hv.w;
    }
    acc = wave_sum(acc);
    if (lane == 0) sattn[s] = acc;
  }
  __syncthreads();
  if (w == 0) {
    float v = sattn[lane];
    float m = v;
    for (int off = 32; off > 0; off >>= 1) m = fmaxf(m, __shfl_xor(m, off));
    float e = expf(v - m);
    float ssum = e;
    for (int off = 32; off > 0; off >>= 1) ssum += __shfl_xor(ssum, off);
    sattn[lane] = e / ssum;
  }
  __syncthreads();
  for (int h = tid; h < 512; h += 256) {
    float c = 0.f;
    for (int s = 0; s < 64; s++) c += sattn[s] * enc[(long)(b * 64 + s) * 512 + h];
    ctx[b * 512 + h] = c;
    cat[(long)(b * 64 + t) * 1024 + 512 + h] = f2b(c);
  }
}

// ---------------- phase 2: LSTM layer 0 (512 blocks: b*16+jg) ---------------
__global__ __launch_bounds__(256) void phase2_k(
    const int* __restrict__ tgt, const float* __restrict__ emb,
    const float* __restrict__ Wih0, const float* __restrict__ Whh0,
    const float* __restrict__ bih0, const float* __restrict__ bhh0,
    const float* __restrict__ ctx,
    const float* __restrict__ h0_old, const float* __restrict__ c0_old,
    float* __restrict__ h0_new, float* __restrict__ c0_new, int t) {
  int bid = blockIdx.x;
  int b = bid >> 4, jg = bid & 15;
  __shared__ __align__(16) float sinp[1536];   // [x | ctx | h0]
  __shared__ float sg[128];
  int tid = threadIdx.x, lane = tid & 63, w = tid >> 6;
  int idx = tgt[b * 64 + t];
  const float* xrow = emb + (long)idx * 512;
  for (int k = tid; k < 512; k += 256) {
    sinp[k] = (idx == 0) ? 0.f : xrow[k];      // padding_idx=0
    sinp[512 + k] = ctx[b * 512 + k];
    sinp[1024 + k] = h0_old[b * 512 + k];
  }
  __syncthreads();
  for (int i = 0; i < 32; i++) {
    int j = w * 512 + jg * 32 + i;             // gate row (w = gate quadrant)
    const float4* w1 = (const float4*)(Wih0 + (long)j * 1024);
    const float4* w2 = (const float4*)(Whh0 + (long)j * 512);
    float acc = 0.f;
    for (int kk = 0; kk < 4; kk++) {
      float4 wv = w1[kk * 64 + lane];
      float4 iv = *(const float4*)&sinp[(kk * 64 + lane) * 4];
      acc += wv.x * iv.x + wv.y * iv.y + wv.z * iv.z + wv.w * iv.w;
    }
    for (int kk = 0; kk < 2; kk++) {
      float4 wv = w2[kk * 64 + lane];
      float4 iv = *(const float4*)&sinp[1024 + (kk * 64 + lane) * 4];
      acc += wv.x * iv.x + wv.y * iv.y + wv.z * iv.z + wv.w * iv.w;
    }
    acc = wave_sum(acc);
    if (lane == 0) sg[w * 32 + i] = acc + bih0[j] + bhh0[j];
  }
  __syncthreads();
  if (tid < 32) {
    int j2 = jg * 32 + tid;
    float ig = sg[tid], fg = sg[32 + tid], gg = sg[64 + tid], og = sg[96 + tid];
    float cold = c0_old[b * 512 + j2];
    float cn = sigm(fg) * cold + sigm(ig) * tanhf(gg);
    float hn = sigm(og) * tanhf(cn);
    c0_new[b * 512 + j2] = cn;
    h0_new[b * 512 + j2] = hn;
  }
}

// ---------------- phase 3: LSTM layer 1 + cat write -------------------------
__global__ __launch_bounds__(256) void phase3_k(
    const float* __restrict__ Wih1, const float* __restrict__ Whh1,
    const float* __restrict__ bih1, const float* __restrict__ bhh1,
    const float* __restrict__ h0_new, const float* __restrict__ h1_old,
    const float* __restrict__ c1_old,
    float* __restrict__ h1_new, float* __restrict__ c1_new,
    short* __restrict__ cat, int t) {
  int bid = blockIdx.x;
  int b = bid >> 4, jg = bid & 15;
  __shared__ __align__(16) float sinp[1024];   // [h0_new | h1_old]
  __shared__ float sg[128];
  int tid = threadIdx.x, lane = tid & 63, w = tid >> 6;
  for (int k = tid; k < 512; k += 256) {
    sinp[k] = h0_new[b * 512 + k];
    sinp[512 + k] = h1_old[b * 512 + k];
  }
  __syncthreads();
  for (int i = 0; i < 32; i++) {
    int j = w * 512 + jg * 32 + i;
    const float4* w1 = (const float4*)(Wih1 + (long)j * 512);
    const float4* w2 = (const float4*)(Whh1 + (long)j * 512);
    float acc = 0.f;
    for (int kk = 0; kk < 2; kk++) {
      float4 wv = w1[kk * 64 + lane];
      float4 iv = *(const float4*)&sinp[(kk * 64 + lane) * 4];
      acc += wv.x * iv.x + wv.y * iv.y + wv.z * iv.z + wv.w * iv.w;
    }
    for (int kk = 0; kk < 2; kk++) {
      float4 wv = w2[kk * 64 + lane];
      float4 iv = *(const float4*)&sinp[512 + (kk * 64 + lane) * 4];
      acc += wv.x * iv.x + wv.y * iv.y + wv.z * iv.z + wv.w * iv.w;
    }
    acc = wave_sum(acc);
    if (lane == 0) sg[w * 32 + i] = acc + bih1[j] + bhh1[j];
  }
  __syncthreads();
  if (tid < 32) {
    int j2 = jg * 32 + tid;
    float ig = sg[tid], fg = sg[32 + tid], gg = sg[64 + tid], og = sg[96 + tid];
    float cold = c1_old[b * 512 + j2];
    float cn = sigm(fg) * cold + sigm(ig) * tanhf(gg);
    float hn = sigm(og) * tanhf(cn);
    c1_new[b * 512 + j2] = cn;
    h1_new[b * 512 + j2] = hn;
    cat[(long)(b * 64 + t) * 1024 + j2] = f2b(hn);
  }
}

// ---------------------------------------------------------------------------
extern "C" void kernel_launch(void* const* d_in, const int* in_sizes, int n_in,
                              void* d_out, int out_size, void* d_ws, size_t ws_size,
                              hipStream_t stream) {
  const int*   tgt    = (const int*)d_in[0];
  const float* enc    = (const float*)d_in[1];
  const float* hidden = (const float*)d_in[2];
  const float* cell   = (const float*)d_in[3];
  const float* emb    = (const float*)d_in[4];
  const float* W_a    = (const float*)d_in[5];
  const float* W_ih0  = (const float*)d_in[6];
  const float* W_hh0  = (const float*)d_in[7];
  const float* b_ih0  = (const float*)d_in[8];
  const float* b_hh0  = (const float*)d_in[9];
  const float* W_ih1  = (const float*)d_in[10];
  const float* W_hh1  = (const float*)d_in[11];
  const float* b_ih1  = (const float*)d_in[12];
  const float* b_hh1  = (const float*)d_in[13];
  const float* W_out  = (const float*)d_in[14];
  const float* b_out  = (const float*)d_in[15];
  float* out = (float*)d_out;

  // ---- workspace carve (~74 MB) ----
  char* p = (char*)d_ws;
  auto alloc = [&](size_t bytes) { void* r = p; p += (bytes + 255) & ~(size_t)255; return r; };
  short* woutB = (short*)alloc(32000ULL * 1024 * 2);
  short* catB  = (short*)alloc(2048ULL * 1024 * 2);
  float* encP  = (float*)alloc(2048ULL * 512 * 4);
  float* ctx   = (float*)alloc(32ULL * 512 * 4);
  float* st    = (float*)alloc(8ULL * 16384 * 4);
  float* h0b = st, *h1b = st + 2 * 16384, *c0b = st + 4 * 16384, *c1b = st + 6 * 16384;

  // ---- prep ----
  hipLaunchKernelGGL(cvt_bf16_k, dim3(4096), dim3(256), 0, stream, W_out, woutB, 32000L * 1024);
  // encP = enc @ W_a in FP32 (recurrence-critical precision)
  hipLaunchKernelGGL(gemm_f32_k, dim3(8, 32), dim3(256), 0, stream,
                     enc, W_a, encP, 2048, 512, 512, 512);
  hipLaunchKernelGGL(init_states_k, dim3(64), dim3(256), 0, stream, hidden, cell,
                     h0b, h1b, c0b, c1b);

  // ---- recurrence: 64 steps x 3 kernels, fp32 state ping-pong ----
  for (int t = 0; t < 64; t++) {
    int o = (t & 1) * 16384, nn = ((t & 1) ^ 1) * 16384;
    hipLaunchKernelGGL(phase1_k, dim3(32), dim3(256), 0, stream,
                       encP, enc, h1b + o, ctx, catB, t);
    hipLaunchKernelGGL(phase2_k, dim3(512), dim3(256), 0, stream,
                       tgt, emb, W_ih0, W_hh0, b_ih0, b_hh0, ctx,
                       h0b + o, c0b + o, h0b + nn, c0b + nn, t);
    hipLaunchKernelGGL(phase3_k, dim3(512), dim3(256), 0, stream,
                       W_ih1, W_hh1, b_ih1, b_hh1,
                       h0b + nn, h1b + o, c1b + o, h1b + nn, c1b + nn, catB, t);
  }

  // ---- final states (after t=63, new state sits in ping-pong slot 0) ----
  hipLaunchKernelGGL(fin_states_k, dim3(64), dim3(256), 0, stream,
                     h0b, h1b, c0b, c1b, out + 65536000L);

  // ---- output projection: [2048x1024] @ [1024x32000] + b_out ----
  hipLaunchKernelGGL(gemm_bf16, dim3(250, 16), dim3(256), 0, stream,
                     catB, woutB, out, b_out,
                     2048, 32000, 1024, 1024, 1024, 32000);
}